// Round 9
// baseline (151.863 us; speedup 1.0000x reference)
//
#include <hip/hip_runtime.h>

#define PP 50
#define TPB 256
#define NBATCH 2048
#define WPB 4                    // waves per block; one wave = one batch
#define NBLK (NBATCH / WPB)      // 512 blocks for all kernels
#define NCOPY 64                 // stat-atomic spreading; == wave width for readback

static constexpr float EPSF = 1e-5f;
static constexpr double INV_ETOT = 1.0 / 5120000.0;   // 1/(B*P*P)

static __device__ __forceinline__ float lrelu(float x) {
    return fmaxf(x, 0.0f) + 0.01f * fminf(x, 0.0f);
}
static __device__ __forceinline__ float rfl(float x) {
    return __int_as_float(__builtin_amdgcn_readfirstlane(__float_as_int(x)));
}

// d_ws: double acc[20*NCOPY]; slots 0-9 = BN1 sum/sumsq, 10-19 = BN2 sum/sumsq.
// Cross-kernel visibility via kernel-boundary cache flush/invalidate.

// ==== K1: BN1 stats via separable per-node sums (d_ij = z_i * w_j) =========
__global__ __launch_bounds__(TPB) void stats1_kernel(
    const float* __restrict__ feat, const float* __restrict__ ang,
    const float* __restrict__ W1, const float* __restrict__ b1,
    double* __restrict__ acc)
{
    __shared__ double bacc[4][10];
    const int t = threadIdx.x;
    const int lane = t & 63;
    const int wv = t >> 6;

    float v0[5], v1[5], v2[5], v3[5], bb1[5];
#pragma unroll
    for (int o = 0; o < 5; ++o) {
        v0[o] = rfl(W1[o*5+0] - W1[o*5+2]);
        v1[o] = rfl(W1[o*5+1] + W1[o*5+2]);
        v2[o] = rfl(W1[o*5+3]);
        v3[o] = rfl(W1[o*5+4]);
        bb1[o] = rfl(b1[o]);
    }

    float f = 0.f, zr = 0.f, zi = 0.f, inv = 0.f;
    if (lane < PP) {
        const int idx = (blockIdx.x * WPB + wv) * PP + lane;
        f = feat[idx];
        float2 a2 = ((const float2*)ang)[idx];
        zr = a2.x; zi = a2.y;
        inv = 1.0f / (zr*zr + zi*zi);
    }
    const float wr = zr * inv, wi = -zi * inv;   // lanes >=50: all zero

    float p[16] = { f, f*f, zr, zi, wr, wi, f*zr, f*zi, f*wr, f*wi,
                    zr*zr, zi*zi, zr*zi, wr*wr, wi*wi, wr*wi };
#pragma unroll
    for (int k = 0; k < 16; ++k) {
        float v = p[k];
#pragma unroll
        for (int off = 32; off > 0; off >>= 1) v += __shfl_down(v, off, 64);
        p[k] = v;
    }
    if (lane == 0) {
        const double P0 = p[0], P1 = p[1], P2 = p[2], P3 = p[3], P4 = p[4];
        const double P5 = p[5], P6 = p[6], P7 = p[7], P8 = p[8], P9 = p[9];
        const double P10 = p[10], P11 = p[11], P12 = p[12];
        const double P13 = p[13], P14 = p[14], P15 = p[15];
        const double Sfi = 50.0 * P0;
        const double Sdr = P2*P4 - P3*P5;
        const double Sdi = P3*P4 + P2*P5;
        const double m00 = 50.0 * P1, m11 = m00, m01 = P0*P0;
        const double m02 = P6*P4 - P7*P5;
        const double m03 = P7*P4 + P6*P5;
        const double m12 = P2*P8 - P3*P9;
        const double m13 = P3*P8 + P2*P9;
        const double m22 = P10*P13 - 2.0*P12*P15 + P11*P14;
        const double m33 = P11*P13 + 2.0*P12*P15 + P10*P14;
        const double m23 = P12*P13 + P10*P15 - P11*P15 - P12*P14;
#pragma unroll
        for (int o = 0; o < 5; ++o) {
            const double a0=v0[o], a1=v1[o], a2=v2[o], a3=v3[o], bo=bb1[o];
            const double sy = a0*Sfi + a1*Sfi + a2*Sdr + a3*Sdi + 2500.0*bo;
            const double q  = a0*a0*m00 + a1*a1*m11 + a2*a2*m22 + a3*a3*m33
                           + 2.0*(a0*a1*m01 + a0*a2*m02 + a0*a3*m03
                                + a1*a2*m12 + a1*a3*m13 + a2*a3*m23);
            bacc[wv][o]   = sy;
            bacc[wv][5+o] = q + 2.0*bo*sy - 2500.0*bo*bo;
        }
    }
    __syncthreads();
    if (t < 10) {
        double s = bacc[0][t] + bacc[1][t] + bacc[2][t] + bacc[3][t];
        atomicAdd(&acc[t * NCOPY + (blockIdx.x & (NCOPY-1))], s);
    }
}

// ==== K2: wave-autonomous edge sweep -> BN2 stats (ZERO barriers) ==========
__global__ __launch_bounds__(TPB) void pass2_kernel(
    const float* __restrict__ feat, const float* __restrict__ ang,
    const float* __restrict__ W1, const float* __restrict__ b1,
    const float* __restrict__ g1, const float* __restrict__ bt1,
    const float* __restrict__ W2, const float* __restrict__ b2,
    double* __restrict__ acc)
{
    __shared__ float4 snd[WPB][PP];          // wave-private regions
    const int t = threadIdx.x;
    const int lane = t & 63;
    const int wv = t >> 6;
    const int batch = blockIdx.x * WPB + wv;

    // own-node global loads first (longest latency)
    float f = 0.f, zr = 0.f, zi = 0.f;
    if (lane < PP) {
        const int idx = batch * PP + lane;
        f = feat[idx];
        float2 a2 = ((const float2*)ang)[idx];
        zr = a2.x; zi = a2.y;
    }

    float v0[5], v1[5], v2[5], v3[5], bb1[5], w2[25], bb2[5];
#pragma unroll
    for (int o = 0; o < 5; ++o) {
        v0[o] = rfl(W1[o*5+0] - W1[o*5+2]);
        v1[o] = rfl(W1[o*5+1] + W1[o*5+2]);
        v2[o] = rfl(W1[o*5+3]);
        v3[o] = rfl(W1[o*5+4]);
        bb1[o] = rfl(b1[o]); bb2[o] = rfl(b2[o]);
    }
#pragma unroll
    for (int i = 0; i < 25; ++i) w2[i] = rfl(W2[i]);

    // BN1 readback: lane-parallel (lane == copy), f64 butterfly -> all lanes
    double tp[10];
#pragma unroll
    for (int s = 0; s < 10; ++s) tp[s] = acc[s * NCOPY + lane];
#pragma unroll
    for (int s = 0; s < 10; ++s) {
#pragma unroll
        for (int off = 32; off > 0; off >>= 1) tp[s] += __shfl_xor(tp[s], off, 64);
    }
    float sc1[5], sh1[5];
#pragma unroll
    for (int o = 0; o < 5; ++o) {
        double mu  = tp[o]   * INV_ETOT;
        double var = tp[5+o] * INV_ETOT - mu * mu;
        float sc = rfl(g1[o]) * rsqrtf((float)var + EPSF);
        sc1[o] = rfl(sc);
        sh1[o] = rfl(rfl(bt1[o]) - (float)mu * sc);
    }

    // stage own batch to wave-private LDS (DS ops of one wave are ordered; no barrier)
    if (lane < PP) {
        snd[wv][lane] = make_float4(f, zr, zi, 1.0f / (zr*zr + zi*zi));
    }

    const float fi = f, ari = zr, aii = zi;   // lanes>=50: zeros -> finite garbage
    float a[10];
#pragma unroll
    for (int k = 0; k < 10; ++k) a[k] = 0.f;

#pragma unroll 10
    for (int pj = 0; pj < PP; ++pj) {
        const float4 nj = snd[wv][pj];       // broadcast read
        const float dr = fmaf(ari, nj.y,  aii*nj.z) * nj.w;
        const float di = fmaf(aii, nj.y, -ari*nj.z) * nj.w;
        float h1[5];
#pragma unroll
        for (int o = 0; o < 5; ++o) {
            float y = fmaf(v0[o], fi, fmaf(v1[o], nj.x,
                      fmaf(v2[o], dr, fmaf(v3[o], di, bb1[o]))));
            h1[o] = lrelu(fmaf(y, sc1[o], sh1[o]));
        }
#pragma unroll
        for (int o = 0; o < 5; ++o) {
            float y = bb2[o];
            y = fmaf(w2[o*5+0], h1[0], y);
            y = fmaf(w2[o*5+1], h1[1], y);
            y = fmaf(w2[o*5+2], h1[2], y);
            y = fmaf(w2[o*5+3], h1[3], y);
            y = fmaf(w2[o*5+4], h1[4], y);
            a[o]   += y;
            a[5+o]  = fmaf(y, y, a[5+o]);
        }
    }
    if (lane >= PP) {
#pragma unroll
        for (int k = 0; k < 10; ++k) a[k] = 0.f;
    }
#pragma unroll
    for (int k = 0; k < 10; ++k) {
#pragma unroll
        for (int off = 32; off > 0; off >>= 1) a[k] += __shfl_xor(a[k], off, 64);
    }
    if (lane == 0) {
        const int copy = batch & (NCOPY - 1);
#pragma unroll
        for (int s = 0; s < 10; ++s)
            atomicAdd(&acc[(10 + s) * NCOPY + copy], (double)a[s]);
    }
}

// ==== K3: wave-autonomous full MLP; lane pi owns dst pi (ZERO barriers) ====
__global__ __launch_bounds__(TPB) void pass3_kernel(
    const float* __restrict__ pt,
    const float* __restrict__ feat, const float* __restrict__ ang,
    const float* __restrict__ W1, const float* __restrict__ b1,
    const float* __restrict__ g1, const float* __restrict__ bt1,
    const float* __restrict__ W2, const float* __restrict__ b2,
    const float* __restrict__ g2, const float* __restrict__ bt2,
    const float* __restrict__ W3, const float* __restrict__ b3,
    const double* __restrict__ acc, float* __restrict__ out)
{
    __shared__ float4 snd[WPB][PP];
    const int t = threadIdx.x;
    const int lane = t & 63;
    const int wv = t >> 6;
    const int batch = blockIdx.x * WPB + wv;

    float f = 0.f, zr = 0.f, zi = 0.f, mypt = 0.f;
    if (lane < PP) {
        const int idx = batch * PP + lane;
        f = feat[idx];
        float2 a2 = ((const float2*)ang)[idx];
        zr = a2.x; zi = a2.y;
        mypt = pt[idx];
    }

    float v0[5], v1[5], v2[5], v3[5], bb1[5], w2[25], bb2[5], w3[25], bb3[5];
#pragma unroll
    for (int o = 0; o < 5; ++o) {
        v0[o] = rfl(W1[o*5+0] - W1[o*5+2]);
        v1[o] = rfl(W1[o*5+1] + W1[o*5+2]);
        v2[o] = rfl(W1[o*5+3]);
        v3[o] = rfl(W1[o*5+4]);
        bb1[o] = rfl(b1[o]); bb2[o] = rfl(b2[o]); bb3[o] = rfl(b3[o]);
    }
#pragma unroll
    for (int i = 0; i < 25; ++i) { w2[i] = rfl(W2[i]); w3[i] = rfl(W3[i]); }

    // BN1+BN2 readback: lane-parallel + butterfly
    double tp[20];
#pragma unroll
    for (int s = 0; s < 20; ++s) tp[s] = acc[s * NCOPY + lane];
#pragma unroll
    for (int s = 0; s < 20; ++s) {
#pragma unroll
        for (int off = 32; off > 0; off >>= 1) tp[s] += __shfl_xor(tp[s], off, 64);
    }
    float sc1[5], sh1[5], sc2[5], sh2[5];
#pragma unroll
    for (int o = 0; o < 5; ++o) {
        double mu1  = tp[o]    * INV_ETOT;
        double var1 = tp[5+o]  * INV_ETOT - mu1 * mu1;
        float s1 = rfl(g1[o]) * rsqrtf((float)var1 + EPSF);
        sc1[o] = rfl(s1);
        sh1[o] = rfl(rfl(bt1[o]) - (float)mu1 * s1);
        double mu2  = tp[10+o] * INV_ETOT;
        double var2 = tp[15+o] * INV_ETOT - mu2 * mu2;
        float s2 = rfl(g2[o]) * rsqrtf((float)var2 + EPSF);
        sc2[o] = rfl(s2);
        sh2[o] = rfl(rfl(bt2[o]) - (float)mu2 * s2);
    }

    if (lane < PP) {
        snd[wv][lane] = make_float4(f, zr, zi, 1.0f / (zr*zr + zi*zi));
    }

    const float fi = f, ari = zr, aii = zi;
    float m[5] = {0.f, 0.f, 0.f, 0.f, 0.f};

#pragma unroll 10
    for (int pj = 0; pj < PP; ++pj) {
        const float4 nj = snd[wv][pj];
        const float dr = fmaf(ari, nj.y,  aii*nj.z) * nj.w;
        const float di = fmaf(aii, nj.y, -ari*nj.z) * nj.w;
        float h1[5], h2[5];
#pragma unroll
        for (int o = 0; o < 5; ++o) {
            float y = fmaf(v0[o], fi, fmaf(v1[o], nj.x,
                      fmaf(v2[o], dr, fmaf(v3[o], di, bb1[o]))));
            h1[o] = lrelu(fmaf(y, sc1[o], sh1[o]));
        }
#pragma unroll
        for (int o = 0; o < 5; ++o) {
            float y = bb2[o];
            y = fmaf(w2[o*5+0], h1[0], y);
            y = fmaf(w2[o*5+1], h1[1], y);
            y = fmaf(w2[o*5+2], h1[2], y);
            y = fmaf(w2[o*5+3], h1[3], y);
            y = fmaf(w2[o*5+4], h1[4], y);
            h2[o] = lrelu(fmaf(y, sc2[o], sh2[o]));
        }
#pragma unroll
        for (int o = 0; o < 5; ++o) {
            float y = bb3[o];
            y = fmaf(w3[o*5+0], h2[0], y);
            y = fmaf(w3[o*5+1], h2[1], y);
            y = fmaf(w3[o*5+2], h2[2], y);
            y = fmaf(w3[o*5+3], h2[3], y);
            y = fmaf(w3[o*5+4], h2[4], y);
            m[o] += y;
        }
    }

    if (lane < PP) {
#pragma unroll
        for (int c = 0; c < 5; ++c) m[c] *= 0.02f;
        float ss, cc;
        sincosf(6.2831853071795865f * m[4], &ss, &cc);
        const int d = batch * PP + lane;
        float* o = out + (size_t)d * 7;
        o[0] = mypt;
        o[1] = m[0];
        o[2] = m[1];
        o[3] = m[2];
        o[4] = m[3];
        o[5] = cc * zr - ss * zi;
        o[6] = cc * zi + ss * zr;
    }
}

extern "C" void kernel_launch(void* const* d_in, const int* in_sizes, int n_in,
                              void* d_out, int out_size, void* d_ws, size_t ws_size,
                              hipStream_t stream)
{
    const float* pt   = (const float*)d_in[0];
    const float* feat = (const float*)d_in[1];
    const float* ang  = (const float*)d_in[2];
    const float* W1   = (const float*)d_in[3];
    const float* b1   = (const float*)d_in[4];
    const float* g1   = (const float*)d_in[5];
    const float* bt1  = (const float*)d_in[6];
    const float* W2   = (const float*)d_in[7];
    const float* b2   = (const float*)d_in[8];
    const float* g2   = (const float*)d_in[9];
    const float* bt2  = (const float*)d_in[10];
    const float* W3   = (const float*)d_in[11];
    const float* b3   = (const float*)d_in[12];
    // d_in[13] = edge_index: closed-form structure (dst=b*P+pi, src=b*P+pj), unused
    float* out  = (float*)d_out;
    double* acc = (double*)d_ws;   // 20*NCOPY doubles

    hipMemsetAsync(d_ws, 0, 20 * NCOPY * sizeof(double), stream);
    stats1_kernel<<<NBLK, TPB, 0, stream>>>(feat, ang, W1, b1, acc);
    pass2_kernel<<<NBLK, TPB, 0, stream>>>(feat, ang, W1, b1, g1, bt1, W2, b2, acc);
    pass3_kernel<<<NBLK, TPB, 0, stream>>>(pt, feat, ang, W1, b1, g1, bt1, W2, b2,
                                           g2, bt2, W3, b3, acc, out);
}